// Round 2
// 1705.709 us; speedup vs baseline: 1.2045x; 1.2045x over previous
//
#include <hip/hip_runtime.h>
#include <stdint.h>

#define DD 4096
#define HH 11008
#define RANK 16
#define NTOK 4096

typedef __attribute__((ext_vector_type(8))) short short8;
typedef __attribute__((ext_vector_type(4))) float f32x4;

static __device__ __forceinline__ unsigned short f2bf(float f) {
    union { float f; uint32_t u; } x; x.f = f;
    uint32_t r = (x.u + 0x7fffu + ((x.u >> 16) & 1u)) >> 16;
    return (unsigned short)r;
}
static __device__ __forceinline__ float bf2f(unsigned short s) {
    union { uint32_t u; float f; } x; x.u = ((uint32_t)s) << 16;
    return x.f;
}

// async global->LDS, 16B per lane; lds dest = wave-uniform base + lane*16
static __device__ __forceinline__ void gl_lds16(const unsigned short* g, unsigned short* l) {
    __builtin_amdgcn_global_load_lds(
        (const __attribute__((address_space(1))) unsigned int*)g,
        (__attribute__((address_space(3))) unsigned int*)l, 16, 0, 0);
}

static __device__ __forceinline__ void barx() {
    __builtin_amdgcn_sched_barrier(0);
    __builtin_amdgcn_s_barrier();
    __builtin_amdgcn_sched_barrier(0);
}
#define VMW(n) do { asm volatile("s_waitcnt vmcnt(" #n ")" ::: "memory"); } while (0)
#define LGW0() do { asm volatile("s_waitcnt lgkmcnt(0)" ::: "memory"); __builtin_amdgcn_sched_barrier(0); } while (0)
#define PRIO1() __builtin_amdgcn_s_setprio(1)
#define PRIO0() __builtin_amdgcn_s_setprio(0)

// ---------------- RMSNorm: fp32 [4096][4096] -> bf16 ----------------
__global__ __launch_bounds__(256) void rmsnorm_kernel(
    const float* __restrict__ data, const float* __restrict__ nw,
    unsigned short* __restrict__ xb) {
    const int row = blockIdx.x;
    const int t = threadIdx.x;
    const float4* dr = (const float4*)(data + (size_t)row * DD);
    float4 v[4];
    float ss = 0.f;
#pragma unroll
    for (int i = 0; i < 4; i++) {
        v[i] = dr[t + 256 * i];
        ss += v[i].x * v[i].x + v[i].y * v[i].y + v[i].z * v[i].z + v[i].w * v[i].w;
    }
#pragma unroll
    for (int off = 32; off > 0; off >>= 1) ss += __shfl_down(ss, off);
    __shared__ float red[4];
    if ((t & 63) == 0) red[t >> 6] = ss;
    __syncthreads();
    float total = red[0] + red[1] + red[2] + red[3];
    float inv = rsqrtf(total / (float)DD + 1e-5f);
    const float4* wr = (const float4*)nw;
    uint2* xo = (uint2*)(xb + (size_t)row * DD);
#pragma unroll
    for (int i = 0; i < 4; i++) {
        float4 w = wr[t + 256 * i];
        union { unsigned short u[4]; uint2 q; } p;
        p.u[0] = f2bf(v[i].x * inv * w.x);
        p.u[1] = f2bf(v[i].y * inv * w.y);
        p.u[2] = f2bf(v[i].z * inv * w.z);
        p.u[3] = f2bf(v[i].w * inv * w.w);
        xo[t + 256 * i] = p.q;
    }
}

// ------------- Transpose + convert: W [K][N] fp32 -> WT [N][K] bf16 -------------
__global__ __launch_bounds__(256) void transpose_cvt(
    const float* __restrict__ W, unsigned short* __restrict__ WT, int K, int N) {
    __shared__ float tile[64][65];
    const int t = threadIdx.x;
    const int n0 = blockIdx.x * 64, k0 = blockIdx.y * 64;
    const int cn = (t & 15) * 4, rk = t >> 4;
#pragma unroll
    for (int p = 0; p < 4; p++) {
        int kk = rk + p * 16;
        float4 v = *(const float4*)(W + (size_t)(k0 + kk) * N + n0 + cn);
        tile[kk][cn] = v.x; tile[kk][cn + 1] = v.y;
        tile[kk][cn + 2] = v.z; tile[kk][cn + 3] = v.w;
    }
    __syncthreads();
    const int n = t >> 2, ks = (t & 3) * 16;
    union { unsigned short u[16]; uint4 q[2]; } pk;
#pragma unroll
    for (int j = 0; j < 16; j++) pk.u[j] = f2bf(tile[ks + j][n]);
    uint4* dst = (uint4*)(WT + (size_t)(n0 + n) * K + k0 + ks);
    dst[0] = pk.q[0];
    dst[1] = pk.q[1];
}

// ------------- LoRA rank projection: t1/t3 = xb @ A1/A3 (16 tokens/block) -------------
__global__ __launch_bounds__(256) void lora_x_kernel(
    const unsigned short* __restrict__ xb, const float* __restrict__ A1,
    const float* __restrict__ A3, float* __restrict__ t1, float* __restrict__ t3) {
    const int row0 = blockIdx.x * 16;
    const int a = row0 >> 10;
    const int t = threadIdx.x;
    const int tok = t >> 4, rk = t & 15;
    __shared__ unsigned short xs[16][264];
    __shared__ float a1s[256][16];
    __shared__ float a3s[256][16];
    float acc1 = 0.f, acc3 = 0.f;
    for (int c = 0; c < DD / 256; c++) {
        const int d0 = c * 256;
        __syncthreads();
#pragma unroll
        for (int i = 0; i < 2; i++) {
            int idx = t + 256 * i;
            int r = idx >> 5, cs = (idx & 31) * 8;
            *(uint4*)&xs[r][cs] = *(const uint4*)(xb + (size_t)(row0 + r) * DD + d0 + cs);
        }
        const float* A1c = A1 + ((size_t)a * DD + d0) * RANK;
        const float* A3c = A3 + ((size_t)a * DD + d0) * RANK;
#pragma unroll
        for (int i = 0; i < 4; i++) {
            int j = (t + 256 * i) * 4;
            *(float4*)&((float*)a1s)[j] = *(const float4*)(A1c + j);
            *(float4*)&((float*)a3s)[j] = *(const float4*)(A3c + j);
        }
        __syncthreads();
#pragma unroll 8
        for (int d = 0; d < 256; d++) {
            float xv = bf2f(xs[tok][d]);
            acc1 += xv * a1s[d][rk];
            acc3 += xv * a3s[d][rk];
        }
    }
    t1[(size_t)(row0 + tok) * RANK + rk] = acc1;
    t3[(size_t)(row0 + tok) * RANK + rk] = acc3;
}

// ------------- LoRA rank projection: t2 = act @ A2 (16 tokens/block) -------------
__global__ __launch_bounds__(256) void lora_act_kernel(
    const unsigned short* __restrict__ act, const float* __restrict__ A2,
    float* __restrict__ t2) {
    const int row0 = blockIdx.x * 16;
    const int a = row0 >> 10;
    const int t = threadIdx.x;
    const int tok = t >> 4, rk = t & 15;
    __shared__ unsigned short xs[16][264];
    __shared__ float a2s[256][16];
    float acc = 0.f;
    for (int c = 0; c < HH / 256; c++) {
        const int d0 = c * 256;
        __syncthreads();
#pragma unroll
        for (int i = 0; i < 2; i++) {
            int idx = t + 256 * i;
            int r = idx >> 5, cs = (idx & 31) * 8;
            *(uint4*)&xs[r][cs] = *(const uint4*)(act + (size_t)(row0 + r) * HH + d0 + cs);
        }
        const float* A2c = A2 + ((size_t)a * HH + d0) * RANK;
#pragma unroll
        for (int i = 0; i < 4; i++) {
            int j = (t + 256 * i) * 4;
            *(float4*)&((float*)a2s)[j] = *(const float4*)(A2c + j);
        }
        __syncthreads();
#pragma unroll 8
        for (int d = 0; d < 256; d++) {
            acc += bf2f(xs[tok][d]) * a2s[d][rk];
        }
    }
    t2[(size_t)(row0 + tok) * RANK + rk] = acc;
}

// ============================================================================
// G1: act = silu(x@W1 + t1@B1) * (x@W3 + t3@B3)
// 256x128 tile, BK=64, 8 waves (2M x 4N), 8-phase schedule, counted vmcnt,
// XOR-swizzled LDS (linear global_load_lds dest + inverse-swizzled source).
// ============================================================================
__global__ __launch_bounds__(512, 2) void gemm1_kernel(
    const unsigned short* __restrict__ xb, const unsigned short* __restrict__ W1T,
    const unsigned short* __restrict__ W3T, const float* __restrict__ t1,
    const float* __restrict__ t3, const float* __restrict__ B1f,
    const float* __restrict__ B3f, unsigned short* __restrict__ act) {
    const int nwg = gridDim.x;                 // 1376, divisible by 8
    const int cpx = nwg >> 3;
    const int bid = blockIdx.x;
    const int wg = (bid & 7) * cpx + (bid >> 3);   // XCD-aware swizzle (bijective)
    const int NTN = HH / 128;                  // 86
    const int m0 = (wg / NTN) * 256;
    const int n0 = (wg % NTN) * 128;
    const int a = m0 >> 10;
    const int t = threadIdx.x;
    const int w = t >> 6, lane = t & 63;
    const int wm = w & 1, wn = w >> 1;
    const int lr = lane & 15, q = lane >> 4;
    const int lrow = lane >> 3;                      // source row within 8-row group
    const int lcol = ((lane & 7) ^ lrow) * 8;        // inverse-swizzled source col

    __shared__ __align__(16) unsigned short lds[65536];  // 128 KiB
    unsigned short* LA  = lds;            // [2][256][64]
    unsigned short* LB1 = lds + 32768;    // [2][128][64]
    unsigned short* LB3 = lds + 49152;    // [2][128][64]

    const unsigned short* gA  = xb  + (size_t)(m0 + lrow) * DD + lcol;
    const unsigned short* gB1 = W1T + (size_t)(n0 + lrow) * DD + lcol;
    const unsigned short* gB3 = W3T + (size_t)(n0 + lrow) * DD + lcol;

#define STG1(gp, lp) do { \
    gl_lds16((gp) + (size_t)(w * 8) * DD,      (lp) + w * 512); \
    gl_lds16((gp) + (size_t)(64 + w * 8) * DD, (lp) + 4096 + w * 512); } while (0)

    f32x4 acc1[8][2], acc3[8][2];
#pragma unroll
    for (int mi = 0; mi < 8; mi++)
#pragma unroll
        for (int nj = 0; nj < 2; nj++) {
            acc1[mi][nj] = (f32x4){0.f, 0.f, 0.f, 0.f};
            acc3[mi][nj] = (f32x4){0.f, 0.f, 0.f, 0.f};
        }
    short8 av[4], b1r[2][2], b3r[2][2];

#define RDA1(d, h, kk) do { _Pragma("unroll") \
    for (int mi = 0; mi < 4; mi++) { int rw = wm * 128 + (h) * 64 + mi * 16 + lr; \
        av[mi] = *reinterpret_cast<const short8*>( \
            &LA[(d) * 16384 + rw * 64 + (((kk) * 32 + q * 8) ^ ((rw & 7) << 3))]); } } while (0)
#define RDB1(d, kk) do { _Pragma("unroll") \
    for (int nj = 0; nj < 2; nj++) { int rw = wn * 32 + nj * 16 + lr; \
        int co = rw * 64 + (((kk) * 32 + q * 8) ^ ((rw & 7) << 3)); \
        b1r[kk][nj] = *reinterpret_cast<const short8*>(&LB1[(d) * 8192 + co]); \
        b3r[kk][nj] = *reinterpret_cast<const short8*>(&LB3[(d) * 8192 + co]); } } while (0)
#define MM1(h, kk) do { _Pragma("unroll") \
    for (int nj = 0; nj < 2; nj++) { _Pragma("unroll") \
        for (int mi = 0; mi < 4; mi++) { \
            acc1[(h) * 4 + mi][nj] = __builtin_amdgcn_mfma_f32_16x16x32_bf16( \
                av[mi], b1r[kk][nj], acc1[(h) * 4 + mi][nj], 0, 0, 0); \
            acc3[(h) * 4 + mi][nj] = __builtin_amdgcn_mfma_f32_16x16x32_bf16( \
                av[mi], b3r[kk][nj], acc3[(h) * 4 + mi][nj], 0, 0, 0); } } } while (0)

    // prologue: tile0 all 4 units, then tile1's B1,B3
    STG1(gA, LA);
    STG1(gA + (size_t)128 * DD, LA + 8192);
    STG1(gB1, LB1);
    STG1(gB3, LB3);
    STG1(gB1 + 64, LB1 + 8192);
    STG1(gB3 + 64, LB3 + 8192);
    VMW(4); barx();

    const int NT = DD / 64;  // 64 K-tiles, 32 iterations
#pragma unroll 1
    for (int it = 0; it < NT / 2; ++it) {
        const int O = 2 * it + 1;
        const int Kc = (2 * it + 2 < NT) ? 2 * it + 2 : NT - 1;  // clamp: garbage ok
        const int Oc = (2 * it + 3 < NT) ? 2 * it + 3 : NT - 1;
        // ph1: E m0-3 k0
        RDA1(0, 0, 0); RDB1(0, 0);
        STG1(gA + (size_t)O * 64, LA + 16384);
        barx(); LGW0(); PRIO1(); MM1(0, 0); PRIO0(); barx();
        // ph2: E m0-3 k1
        RDA1(0, 0, 1); RDB1(0, 1);
        STG1(gA + (size_t)O * 64 + (size_t)128 * DD, LA + 16384 + 8192);
        barx(); LGW0(); PRIO1(); MM1(0, 1); PRIO0(); barx();
        // ph3: E m4-7 k0
        RDA1(0, 1, 0);
        STG1(gB1 + (size_t)Kc * 64, LB1);
        barx(); LGW0(); PRIO1(); MM1(1, 0); PRIO0(); barx();
        // ph4: E m4-7 k1
        RDA1(0, 1, 1);
        STG1(gB3 + (size_t)Kc * 64, LB3);
        barx(); LGW0(); PRIO1(); MM1(1, 1); PRIO0(); VMW(4); barx();
        // ph5: O m0-3 k0
        RDA1(1, 0, 0); RDB1(1, 0);
        STG1(gA + (size_t)Kc * 64, LA);
        barx(); LGW0(); PRIO1(); MM1(0, 0); PRIO0(); barx();
        // ph6: O m0-3 k1
        RDA1(1, 0, 1); RDB1(1, 1);
        STG1(gA + (size_t)Kc * 64 + (size_t)128 * DD, LA + 8192);
        barx(); LGW0(); PRIO1(); MM1(0, 1); PRIO0(); barx();
        // ph7: O m4-7 k0
        RDA1(1, 1, 0);
        STG1(gB1 + (size_t)Oc * 64, LB1 + 8192);
        barx(); LGW0(); PRIO1(); MM1(1, 0); PRIO0(); barx();
        // ph8: O m4-7 k1
        RDA1(1, 1, 1);
        STG1(gB3 + (size_t)Oc * 64, LB3 + 8192);
        barx(); LGW0(); PRIO1(); MM1(1, 1); PRIO0(); VMW(4); barx();
    }

    // drain all in-flight global_load_lds before reusing LDS
    VMW(0); barx();

    // --- LoRA K-extension: pack rank-16 tiles (swizzled writes) + one MFMA k-step ---
    {
        const int arow = t >> 1, hf = t & 1;
        uint4 z; z.x = z.y = z.z = z.w = 0u;
        const int sw = (arow & 7) << 3;
        const float4* tp1 = (const float4*)(t1 + (size_t)(m0 + arow) * RANK + hf * 8);
        float4 u0 = tp1[0], u1 = tp1[1];
        union { unsigned short u[8]; uint4 qv; } pa;
        pa.u[0] = f2bf(u0.x); pa.u[1] = f2bf(u0.y); pa.u[2] = f2bf(u0.z); pa.u[3] = f2bf(u0.w);
        pa.u[4] = f2bf(u1.x); pa.u[5] = f2bf(u1.y); pa.u[6] = f2bf(u1.z); pa.u[7] = f2bf(u1.w);
        *(uint4*)&LA[arow * 64 + ((hf * 8) ^ sw)] = pa.qv;
        *(uint4*)&LA[arow * 64 + ((16 + hf * 8) ^ sw)] = z;
        const float4* tp3 = (const float4*)(t3 + (size_t)(m0 + arow) * RANK + hf * 8);
        float4 v0 = tp3[0], v1 = tp3[1];
        pa.u[0] = f2bf(v0.x); pa.u[1] = f2bf(v0.y); pa.u[2] = f2bf(v0.z); pa.u[3] = f2bf(v0.w);
        pa.u[4] = f2bf(v1.x); pa.u[5] = f2bf(v1.y); pa.u[6] = f2bf(v1.z); pa.u[7] = f2bf(v1.w);
        *(uint4*)&LA[16384 + arow * 64 + ((hf * 8) ^ sw)] = pa.qv;
        *(uint4*)&LA[16384 + arow * 64 + ((16 + hf * 8) ^ sw)] = z;
        // B1 (waves 0-3) / B3 (waves 4-7): 128 n-rows each
        const int n = (t & 255) >> 1;
        const float* Bsrc = (t < 256) ? B1f : B3f;
        unsigned short* Ldst = (t < 256) ? LB1 : LB3;
        union { unsigned short u[8]; uint4 qv; } pb;
#pragma unroll
        for (int j = 0; j < 8; j++)
            pb.u[j] = f2bf(Bsrc[((size_t)a * RANK + hf * 8 + j) * HH + n0 + n]);
        const int swn = (n & 7) << 3;
        *(uint4*)&Ldst[n * 64 + ((hf * 8) ^ swn)] = pb.qv;
        *(uint4*)&Ldst[n * 64 + ((16 + hf * 8) ^ swn)] = z;
    }
    __syncthreads();
    {
        short8 la[8];
#pragma unroll
        for (int mi = 0; mi < 8; mi++) {
            int rw = wm * 128 + mi * 16 + lr;
            la[mi] = *reinterpret_cast<const short8*>(&LA[rw * 64 + ((q * 8) ^ ((rw & 7) << 3))]);
        }
#pragma unroll
        for (int nj = 0; nj < 2; nj++) {
            int rw = wn * 32 + nj * 16 + lr;
            short8 b1 = *reinterpret_cast<const short8*>(&LB1[rw * 64 + ((q * 8) ^ ((rw & 7) << 3))]);
#pragma unroll
            for (int mi = 0; mi < 8; mi++)
                acc1[mi][nj] = __builtin_amdgcn_mfma_f32_16x16x32_bf16(la[mi], b1, acc1[mi][nj], 0, 0, 0);
        }
#pragma unroll
        for (int mi = 0; mi < 8; mi++) {
            int rw = wm * 128 + mi * 16 + lr;
            la[mi] = *reinterpret_cast<const short8*>(&LA[16384 + rw * 64 + ((q * 8) ^ ((rw & 7) << 3))]);
        }
#pragma unroll
        for (int nj = 0; nj < 2; nj++) {
            int rw = wn * 32 + nj * 16 + lr;
            short8 b3 = *reinterpret_cast<const short8*>(&LB3[rw * 64 + ((q * 8) ^ ((rw & 7) << 3))]);
#pragma unroll
            for (int mi = 0; mi < 8; mi++)
                acc3[mi][nj] = __builtin_amdgcn_mfma_f32_16x16x32_bf16(la[mi], b3, acc3[mi][nj], 0, 0, 0);
        }
    }

    // --- epilogue: silu(h1)*h3 -> bf16 ---
#pragma unroll
    for (int mi = 0; mi < 8; mi++)
#pragma unroll
        for (int nj = 0; nj < 2; nj++)
#pragma unroll
            for (int rg = 0; rg < 4; rg++) {
                int row = wm * 128 + mi * 16 + q * 4 + rg;
                int col = wn * 32 + nj * 16 + lr;
                float h1 = acc1[mi][nj][rg];
                float h3 = acc3[mi][nj][rg];
                float sig = 1.f / (1.f + __expf(-h1));
                act[(size_t)(m0 + row) * HH + n0 + col] = f2bf(h1 * sig * h3);
            }
#undef STG1
#undef RDA1
#undef RDB1
#undef MM1
}

// ============================================================================
// G2: out = act@W2 + t2@B2 — 256x256 tile, BK=64, same 8-phase schedule
// ============================================================================
__global__ __launch_bounds__(512, 2) void gemm2_kernel(
    const unsigned short* __restrict__ actb, const unsigned short* __restrict__ W2T,
    const float* __restrict__ t2, const float* __restrict__ B2f,
    float* __restrict__ out) {
    const int nwg = gridDim.x;                 // 256
    const int cpx = nwg >> 3;
    const int bid = blockIdx.x;
    const int wg = (bid & 7) * cpx + (bid >> 3);
    const int NTN = DD / 256;                  // 16
    const int m0 = (wg / NTN) * 256;
    const int n0 = (wg % NTN) * 256;
    const int a = m0 >> 10;
    const int t = threadIdx.x;
    const int w = t >> 6, lane = t & 63;
    const int wm = w & 1, wn = w >> 1;
    const int lr = lane & 15, q = lane >> 4;
    const int lrow = lane >> 3;
    const int lcol = ((lane & 7) ^ lrow) * 8;

    __shared__ __align__(16) unsigned short lds[65536];  // 128 KiB
    unsigned short* LA = lds;            // [2][256][64]
    unsigned short* LB = lds + 32768;    // [2][256][64]

    const unsigned short* gA = actb + (size_t)(m0 + lrow) * HH + lcol;
    const unsigned short* gB = W2T  + (size_t)(n0 + lrow) * HH + lcol;

#define STG2(gp, lp) do { \
    gl_lds16((gp) + (size_t)(w * 8) * HH,      (lp) + w * 512); \
    gl_lds16((gp) + (size_t)(64 + w * 8) * HH, (lp) + 4096 + w * 512); } while (0)

    f32x4 acc[8][4];
#pragma unroll
    for (int mi = 0; mi < 8; mi++)
#pragma unroll
        for (int nj = 0; nj < 4; nj++) acc[mi][nj] = (f32x4){0.f, 0.f, 0.f, 0.f};
    short8 av[4], br[2][4];

#define RDA2(d, h, kk) do { _Pragma("unroll") \
    for (int mi = 0; mi < 4; mi++) { int rw = wm * 128 + (h) * 64 + mi * 16 + lr; \
        av[mi] = *reinterpret_cast<const short8*>( \
            &LA[(d) * 16384 + rw * 64 + (((kk) * 32 + q * 8) ^ ((rw & 7) << 3))]); } } while (0)
#define RDB2(d, kk) do { _Pragma("unroll") \
    for (int nj = 0; nj < 4; nj++) { int rw = wn * 64 + nj * 16 + lr; \
        br[kk][nj] = *reinterpret_cast<const short8*>( \
            &LB[(d) * 16384 + rw * 64 + (((kk) * 32 + q * 8) ^ ((rw & 7) << 3))]); } } while (0)
#define MM2(h, kk) do { _Pragma("unroll") \
    for (int nj = 0; nj < 4; nj++) { _Pragma("unroll") \
        for (int mi = 0; mi < 4; mi++) { \
            acc[(h) * 4 + mi][nj] = __builtin_amdgcn_mfma_f32_16x16x32_bf16( \
                av[mi], br[kk][nj], acc[(h) * 4 + mi][nj], 0, 0, 0); } } } while (0)

    // prologue: tile0 all 4 units, then tile1's B0,B1
    STG2(gA, LA);
    STG2(gA + (size_t)128 * HH, LA + 8192);
    STG2(gB, LB);
    STG2(gB + (size_t)128 * HH, LB + 8192);
    STG2(gB + 64, LB + 16384);
    STG2(gB + 64 + (size_t)128 * HH, LB + 16384 + 8192);
    VMW(4); barx();

    const int NT = HH / 64;  // 172 K-tiles, 86 iterations
#pragma unroll 1
    for (int it = 0; it < NT / 2; ++it) {
        const int O = 2 * it + 1;
        const int Kc = (2 * it + 2 < NT) ? 2 * it + 2 : NT - 1;
        const int Oc = (2 * it + 3 < NT) ? 2 * it + 3 : NT - 1;
        // ph1
        RDA2(0, 0, 0); RDB2(0, 0);
        STG2(gA + (size_t)O * 64, LA + 16384);
        barx(); LGW0(); PRIO1(); MM2(0, 0); PRIO0(); barx();
        // ph2
        RDA2(0, 0, 1); RDB2(0, 1);
        STG2(gA + (size_t)O * 64 + (size_t)128 * HH, LA + 16384 + 8192);
        barx(); LGW0(); PRIO1(); MM2(0, 1); PRIO0(); barx();
        // ph3
        RDA2(0, 1, 0);
        STG2(gB + (size_t)Kc * 64, LB);
        barx(); LGW0(); PRIO1(); MM2(1, 0); PRIO0(); barx();
        // ph4
        RDA2(0, 1, 1);
        STG2(gB + (size_t)Kc * 64 + (size_t)128 * HH, LB + 8192);
        barx(); LGW0(); PRIO1(); MM2(1, 1); PRIO0(); VMW(4); barx();
        // ph5
        RDA2(1, 0, 0); RDB2(1, 0);
        STG2(gA + (size_t)Kc * 64, LA);
        barx(); LGW0(); PRIO1(); MM2(0, 0); PRIO0(); barx();
        // ph6
        RDA2(1, 0, 1); RDB2(1, 1);
        STG2(gA + (size_t)Kc * 64 + (size_t)128 * HH, LA + 8192);
        barx(); LGW0(); PRIO1(); MM2(0, 1); PRIO0(); barx();
        // ph7
        RDA2(1, 1, 0);
        STG2(gB + (size_t)Oc * 64, LB + 16384);
        barx(); LGW0(); PRIO1(); MM2(1, 0); PRIO0(); barx();
        // ph8
        RDA2(1, 1, 1);
        STG2(gB + (size_t)Oc * 64 + (size_t)128 * HH, LB + 16384 + 8192);
        barx(); LGW0(); PRIO1(); MM2(1, 1); PRIO0(); VMW(4); barx();
    }

    VMW(0); barx();

    // --- LoRA K-extension: acc += t2_tile @ B2^T ---
    {
        const int arow = t >> 1, hf = t & 1;
        uint4 z; z.x = z.y = z.z = z.w = 0u;
        const int sw = (arow & 7) << 3;
        const float4* tp = (const float4*)(t2 + (size_t)(m0 + arow) * RANK + hf * 8);
        float4 u0 = tp[0], u1 = tp[1];
        union { unsigned short u[8]; uint4 qv; } pa;
        pa.u[0] = f2bf(u0.x); pa.u[1] = f2bf(u0.y); pa.u[2] = f2bf(u0.z); pa.u[3] = f2bf(u0.w);
        pa.u[4] = f2bf(u1.x); pa.u[5] = f2bf(u1.y); pa.u[6] = f2bf(u1.z); pa.u[7] = f2bf(u1.w);
        *(uint4*)&LA[arow * 64 + ((hf * 8) ^ sw)] = pa.qv;
        *(uint4*)&LA[arow * 64 + ((16 + hf * 8) ^ sw)] = z;
        // B2^T tile: 256 n-rows
        const int n = t >> 1;
        union { unsigned short u[8]; uint4 qv; } pb;
#pragma unroll
        for (int j = 0; j < 8; j++)
            pb.u[j] = f2bf(B2f[((size_t)a * RANK + hf * 8 + j) * DD + n0 + n]);
        const int swn = (n & 7) << 3;
        *(uint4*)&LB[n * 64 + ((hf * 8) ^ swn)] = pb.qv;
        *(uint4*)&LB[n * 64 + ((16 + hf * 8) ^ swn)] = z;
    }
    __syncthreads();
    {
        short8 la[8];
#pragma unroll
        for (int mi = 0; mi < 8; mi++) {
            int rw = wm * 128 + mi * 16 + lr;
            la[mi] = *reinterpret_cast<const short8*>(&LA[rw * 64 + ((q * 8) ^ ((rw & 7) << 3))]);
        }
#pragma unroll
        for (int nj = 0; nj < 4; nj++) {
            int rw = wn * 64 + nj * 16 + lr;
            short8 b = *reinterpret_cast<const short8*>(&LB[rw * 64 + ((q * 8) ^ ((rw & 7) << 3))]);
#pragma unroll
            for (int mi = 0; mi < 8; mi++)
                acc[mi][nj] = __builtin_amdgcn_mfma_f32_16x16x32_bf16(la[mi], b, acc[mi][nj], 0, 0, 0);
        }
    }

#pragma unroll
    for (int mi = 0; mi < 8; mi++)
#pragma unroll
        for (int nj = 0; nj < 4; nj++)
#pragma unroll
            for (int rg = 0; rg < 4; rg++) {
                int row = wm * 128 + mi * 16 + q * 4 + rg;
                int col = wn * 64 + nj * 16 + lr;
                out[(size_t)(m0 + row) * DD + n0 + col] = acc[mi][nj][rg];
            }
#undef STG2
#undef RDA2
#undef RDB2
#undef MM2
}

// ---------------- launch ----------------
extern "C" void kernel_launch(void* const* d_in, const int* in_sizes, int n_in,
                              void* d_out, int out_size, void* d_ws, size_t ws_size,
                              hipStream_t stream) {
    const float* data = (const float*)d_in[0];
    const float* norm_w = (const float*)d_in[1];
    const float* W1 = (const float*)d_in[2];
    const float* W3 = (const float*)d_in[3];
    const float* W2 = (const float*)d_in[4];
    const float* A1 = (const float*)d_in[5];
    const float* B1 = (const float*)d_in[6];
    const float* A3 = (const float*)d_in[7];
    const float* B3 = (const float*)d_in[8];
    const float* A2 = (const float*)d_in[9];
    const float* B2 = (const float*)d_in[10];
    float* out = (float*)d_out;

    char* ws = (char*)d_ws;
    const size_t WT_BYTES = (size_t)DD * HH * 2;         // 90,177,536
    unsigned short* W1T = (unsigned short*)(ws + 0);
    unsigned short* W3T = (unsigned short*)(ws + WT_BYTES);
    unsigned short* W2T = (unsigned short*)(ws + 0);     // reuse after gemm1
    unsigned short* xb  = (unsigned short*)(ws + 2 * WT_BYTES);
    unsigned short* act = (unsigned short*)(ws + 2 * WT_BYTES + (size_t)NTOK * DD * 2);
    float* t1 = (float*)(ws + 2 * WT_BYTES + (size_t)NTOK * DD * 2 + (size_t)NTOK * HH * 2);
    float* t3 = t1 + (size_t)NTOK * RANK;
    float* t2 = t3 + (size_t)NTOK * RANK;

    rmsnorm_kernel<<<NTOK, 256, 0, stream>>>(data, norm_w, xb);
    transpose_cvt<<<dim3(HH / 64, DD / 64), 256, 0, stream>>>(W1, W1T, DD, HH);
    transpose_cvt<<<dim3(HH / 64, DD / 64), 256, 0, stream>>>(W3, W3T, DD, HH);
    lora_x_kernel<<<NTOK / 16, 256, 0, stream>>>(xb, A1, A3, t1, t3);
    gemm1_kernel<<<dim3((NTOK / 256) * (HH / 128)), 512, 0, stream>>>(xb, W1T, W3T, t1, t3, B1, B3, act);
    transpose_cvt<<<dim3(DD / 64, HH / 64), 256, 0, stream>>>(W2, W2T, HH, DD);
    lora_act_kernel<<<NTOK / 16, 256, 0, stream>>>(act, A2, t2);
    gemm2_kernel<<<dim3((NTOK / 256) * (DD / 256)), 512, 0, stream>>>(act, W2T, t2, B2, out);
}